// Round 3
// baseline (73.178 us; speedup 1.0000x reference)
//
#include <hip/hip_runtime.h>

// STFT -> ISTFT round-trip with matched pinv bases is algebraically the
// identity on the input: the kernel is a pure D2D copy of 32*160000 fp32
// (20.48 MB read + 20.48 MB write).
//
// V2b: same design as V2 (4 independent 16B accesses per thread, exact
// grid, nontemporal streaming), but using a native Clang ext_vector_type
// instead of HIP's float4 class — __builtin_nontemporal_{load,store}
// requires a scalar-or-vector pointee and rejects HIP_vector_type
// (that was V2's compile failure).

typedef float f4 __attribute__((ext_vector_type(4)));

#define BLOCK 256
#define UNROLL 4

__global__ __launch_bounds__(BLOCK) void identity_copy_f4x4(
    const f4* __restrict__ src, f4* __restrict__ dst, int n4) {
    const int base = blockIdx.x * (BLOCK * UNROLL) + threadIdx.x;

    if (base + BLOCK * (UNROLL - 1) < n4) {
        // Fast path: 4 independent 16B loads back-to-back (4x MLP), then
        // 4 nontemporal 16B stores. Each instruction is a fully-coalesced
        // 1 KB wave access.
        f4 v0 = __builtin_nontemporal_load(&src[base]);
        f4 v1 = __builtin_nontemporal_load(&src[base + BLOCK]);
        f4 v2 = __builtin_nontemporal_load(&src[base + 2 * BLOCK]);
        f4 v3 = __builtin_nontemporal_load(&src[base + 3 * BLOCK]);
        __builtin_nontemporal_store(v0, &dst[base]);
        __builtin_nontemporal_store(v1, &dst[base + BLOCK]);
        __builtin_nontemporal_store(v2, &dst[base + 2 * BLOCK]);
        __builtin_nontemporal_store(v3, &dst[base + 3 * BLOCK]);
    } else {
        // Tail path (at most the last block lands here).
        #pragma unroll
        for (int u = 0; u < UNROLL; ++u) {
            const int i = base + u * BLOCK;
            if (i < n4) {
                f4 v = __builtin_nontemporal_load(&src[i]);
                __builtin_nontemporal_store(v, &dst[i]);
            }
        }
    }
}

extern "C" void kernel_launch(void* const* d_in, const int* in_sizes, int n_in,
                              void* d_out, int out_size, void* d_ws, size_t ws_size,
                              hipStream_t stream) {
    const float* x = (const float*)d_in[0];
    float* out = (float*)d_out;

    // out_size == 32*160000 == 5,120,000 floats (divisible by 4)
    const int n4 = out_size / 4;                       // 1,280,000 f4s
    const int per_block = BLOCK * UNROLL;              // 1024 f4s/block
    const int grid = (n4 + per_block - 1) / per_block; // 1250 blocks exactly

    identity_copy_f4x4<<<grid, BLOCK, 0, stream>>>(
        (const f4*)x, (f4*)out, n4);
}

// Round 4
// 69.898 us; speedup vs baseline: 1.0469x; 1.0469x over previous
//
#include <hip/hip_runtime.h>

// STFT -> ISTFT round-trip with matched pinv bases is algebraically the
// identity on the input: the kernel is a pure D2D copy of 32*160000 fp32
// (20.48 MB read + 20.48 MB write).
//
// V3: use the vendor blit path (hipMemcpyAsync D2D) instead of a custom
// copy kernel. Evidence: V2b's 4x-MLP + exact-grid + nontemporal redesign
// changed nothing vs the naive grid-stride copy (dur 69.9 -> 73.2, within
// session noise; implied copy+overhead residual ~26-28 us in both), so the
// residual is not thread-level copy throughput. The runtime's blit path is
// the same code family as the fillBufferAligned kernels that sustain
// 6 TB/s in this exact trace, and hipMemcpyAsync(..., stream) is
// graph-capture-safe per the harness rules.

extern "C" void kernel_launch(void* const* d_in, const int* in_sizes, int n_in,
                              void* d_out, int out_size, void* d_ws, size_t ws_size,
                              hipStream_t stream) {
    // out_size == 32*160000 == 5,120,000 floats == 20.48 MB
    hipMemcpyAsync(d_out, d_in[0], (size_t)out_size * sizeof(float),
                   hipMemcpyDeviceToDevice, stream);
}